// Round 5
// baseline (466.312 us; speedup 1.0000x reference)
//
#include <hip/hip_runtime.h>
#include <stdint.h>

typedef __attribute__((ext_vector_type(8))) short bf16x8_t;  // 8 bf16 in 4 VGPRs
typedef __attribute__((ext_vector_type(4))) float f32x4_t;   // MFMA accumulator

#define BM2 256
#define BN2 256

// ---------- helpers ----------

__device__ __forceinline__ unsigned short f2bf_rn(float f) {
    unsigned int u = __float_as_uint(f);
    u += 0x7fffu + ((u >> 16) & 1u);   // round-to-nearest-even
    return (unsigned short)(u >> 16);
}

// one packed byte (as int32 in [0,256)) -> two bf16 (q-8), low nibble = even k
__device__ __forceinline__ unsigned int dq2(int v) {
    float f0 = (float)((v & 15) - 8);
    float f1 = (float)(((v >> 4) & 15) - 8);
    return (__float_as_uint(f0) >> 16) | (__float_as_uint(f1) & 0xffff0000u);
}

__device__ __forceinline__ void gload_lds16(const void* g, void* l) {
    __builtin_amdgcn_global_load_lds(
        (__attribute__((address_space(1))) void*)g,
        (__attribute__((address_space(3))) void*)l, 16, 0, 0);
}

// ---------- pre-pass kernels: emit TILED kq-major bf16 layout ----------
// Dest layout (16B chunks): [rowblk256][kt(K/64)][kq(4)][slot(512)]
//   slot = (row&255)*2 + chp,  chp = (kc&1) ^ ((row>>2)&1)   (bank swizzle)
// Each kq block (8 KB) is CONTIGUOUS -> GEMM stages it linearly via
// global_load_lds; fragment ds_reads use chp=(fq&1)^((fr>>2)&1) ->
// conflict-free (verified R2/R4: SQ_LDS_BANK_CONFLICT = 0).

__device__ __forceinline__ int tiled_dest(int r, int kc, int nkt) {
    int rb = r & 255;
    int kt = kc >> 3, kcl = kc & 7;
    int kq = kcl >> 1, ch = kcl & 1;
    int chp = ch ^ ((rb >> 2) & 1);
    return ((((r >> 8) * nkt + kt) * 4 + kq) << 9) + rb * 2 + chp;
}

__global__ void cvt_x_kernel(const float4* __restrict__ x4,
                             uint4* __restrict__ o4, int nchunks, int cpr, int nkt) {
    int stride = gridDim.x * blockDim.x;
    for (int i = blockIdx.x * blockDim.x + threadIdx.x; i < nchunks; i += stride) {
        int r = i / cpr, kc = i - r * cpr;
        float4 v0 = x4[2 * i];
        float4 v1 = x4[2 * i + 1];
        uint4 o;
        o.x = (unsigned)f2bf_rn(v0.x) | ((unsigned)f2bf_rn(v0.y) << 16);
        o.y = (unsigned)f2bf_rn(v0.z) | ((unsigned)f2bf_rn(v0.w) << 16);
        o.z = (unsigned)f2bf_rn(v1.x) | ((unsigned)f2bf_rn(v1.y) << 16);
        o.w = (unsigned)f2bf_rn(v1.z) | ((unsigned)f2bf_rn(v1.w) << 16);
        o4[tiled_dest(r, kc, nkt)] = o;
    }
}

__global__ void dequant_w_kernel(const int4* __restrict__ pw4,
                                 uint4* __restrict__ o4, int nchunks, int cpr, int nkt) {
    int stride = gridDim.x * blockDim.x;
    for (int i = blockIdx.x * blockDim.x + threadIdx.x; i < nchunks; i += stride) {
        int r = i / cpr, kc = i - r * cpr;
        int4 v = pw4[i];
        uint4 o;
        o.x = dq2(v.x); o.y = dq2(v.y); o.z = dq2(v.z); o.w = dq2(v.w);
        o4[tiled_dest(r, kc, nkt)] = o;
    }
}

// ---------- main GEMM: 256x256x64, 8 waves, 2-phase + 1-phase READ SKEW ------
// Phase q (q=2t+p): STAGE group q+2 -> vmcnt(4) [retires group q+1, keeps the
// just-issued 4 in flight] -> barrier -> read B frags (group q, 4xb128) ->
// PREFETCH A frags for group q+1 (8xb128) -> lgkmcnt(8) [retires old A + B,
// keeps prefetch streaming] -> 32 MFMA on previous-phase A regs.
// LDS delivery (~1150 cyc/CU-phase) thus overlaps MFMA issue (~1242 cyc)
// instead of serializing with it (R4: 2375 cyc/phase observed = sum).
// Race ledger: RAW: group q+1 per-wave vmcnt-retired pre-barrier at phase q,
// read post-barrier -> all waves' loads landed. WAR: region of group g is
// re-staged at phase g+2, >=2 barriers after its reads lgkm-retire at phase g.
// A-frag double-buffer alternates by STATIC phase parity (rule #20).

__global__ __launch_bounds__(512, 2) void qlin_gemm256(
    const short* __restrict__ Xb, const short* __restrict__ Wb,
    const float* __restrict__ scales, const float* __restrict__ bias,
    float* __restrict__ Y, int M, int N, int K)
{
    __shared__ short As[2][4][4096];   // [buf][kq][512 slots x 8 shorts] = 64 KB
    __shared__ short Bs[2][4][4096];   // 64 KB

    int nbm = M >> 8, nbn = N >> 8, nkt = K >> 6;
    int nwg = nbm * nbn;
    // bijective XCD swizzle (m204 form)
    int bid = blockIdx.x;
    int q8 = nwg >> 3, r8 = nwg & 7;
    int xcd = bid & 7, lid = bid >> 3;
    int wgid = (xcd < r8 ? xcd * (q8 + 1) : r8 * (q8 + 1) + (xcd - r8) * q8) + lid;
    int bm = wgid % nbm, bn = wgid / nbm;

    const short* ga = Xb + (size_t)bm * nkt * 16384;
    const short* gb = Wb + (size_t)bn * nkt * 16384;

    int tid = threadIdx.x, lane = tid & 63, wid = tid >> 6;
    int wr = wid >> 2, wc = wid & 3;          // 2x4 wave grid, per-wave out 128x64
    int fr = lane & 15, fq = lane >> 4;       // frag row / k-subchunk
    int chp = (fq & 1) ^ ((fr >> 2) & 1);     // lane-constant chunk swizzle

    f32x4_t acc[8][4] = {};

    int lsel = (fq >> 1) * 4096 + fr * 16 + chp * 8;
    int arow = wr * 2048;                     // (wr*128 rows)*16 shorts
    int brow = wc * 1024;                     // (wc*64 rows)*16 shorts

#define STAGE(tt, h)                                                          \
    do {                                                                      \
        int blk_ = (((tt) << 2) + ((h) << 1));                                \
        int b_ = (tt) & 1;                                                    \
        gload_lds16(ga + (size_t)blk_ * 4096 + tid * 8,                       \
                    &As[b_][(h) << 1][wid * 512]);                            \
        gload_lds16(gb + (size_t)blk_ * 4096 + tid * 8,                       \
                    &Bs[b_][(h) << 1][wid * 512]);                            \
        gload_lds16(ga + (size_t)(blk_ + 1) * 4096 + tid * 8,                 \
                    &As[b_][((h) << 1) + 1][wid * 512]);                      \
        gload_lds16(gb + (size_t)(blk_ + 1) * 4096 + tid * 8,                 \
                    &Bs[b_][((h) << 1) + 1][wid * 512]);                      \
    } while (0)

    // prologue: stage tile 0 (groups 0 and 1)
    STAGE(0, 0);
    STAGE(0, 1);

    bf16x8_t afP[8], afN[8], bf[4];
    int nt = nkt;

    for (int t = 0; t < nt; ++t) {
        // ---------------- phase p = 0 (group 2t): MFMA afP, prefetch afN ----
        {
            if (t + 1 < nt) {
                STAGE(t + 1, 0);
                asm volatile("s_waitcnt vmcnt(4)" ::: "memory");
            } else {
                asm volatile("s_waitcnt vmcnt(0)" ::: "memory");
            }
            __builtin_amdgcn_s_barrier();
            __builtin_amdgcn_sched_barrier(0);

            const short* Ak = &As[t & 1][0][0];
            const short* Bk = &Bs[t & 1][0][0];
            if (t == 0) {
                #pragma unroll
                for (int m = 0; m < 8; ++m)
                    afP[m] = *(const bf16x8_t*)&Ak[lsel + arow + m * 256];
            }
            #pragma unroll
            for (int n = 0; n < 4; ++n)
                bf[n] = *(const bf16x8_t*)&Bk[lsel + brow + n * 256];
            // prefetch A frags for group 2t+1 (same buffer, kq blocks 2..3)
            const short* An = &As[t & 1][2][0];
            #pragma unroll
            for (int m = 0; m < 8; ++m)
                afN[m] = *(const bf16x8_t*)&An[lsel + arow + m * 256];
            asm volatile("s_waitcnt lgkmcnt(8)" ::: "memory");
            __builtin_amdgcn_sched_barrier(0);

            __builtin_amdgcn_s_setprio(1);
            #pragma unroll
            for (int m = 0; m < 8; ++m)
                #pragma unroll
                for (int n = 0; n < 4; ++n)
                    acc[m][n] = __builtin_amdgcn_mfma_f32_16x16x32_bf16(
                        afP[m], bf[n], acc[m][n], 0, 0, 0);
            __builtin_amdgcn_s_setprio(0);
        }
        // ---------------- phase p = 1 (group 2t+1): MFMA afN, prefetch afP --
        {
            if (t + 1 < nt) {
                STAGE(t + 1, 1);
                asm volatile("s_waitcnt vmcnt(4)" ::: "memory");
            } else {
                asm volatile("s_waitcnt vmcnt(0)" ::: "memory");
            }
            __builtin_amdgcn_s_barrier();
            __builtin_amdgcn_sched_barrier(0);

            const short* Bk = &Bs[t & 1][2][0];
            #pragma unroll
            for (int n = 0; n < 4; ++n)
                bf[n] = *(const bf16x8_t*)&Bk[lsel + brow + n * 256];
            if (t + 1 < nt) {
                // prefetch A frags for group 2(t+1) (other buffer, kq 0..1)
                const short* An = &As[(t + 1) & 1][0][0];
                #pragma unroll
                for (int m = 0; m < 8; ++m)
                    afP[m] = *(const bf16x8_t*)&An[lsel + arow + m * 256];
                asm volatile("s_waitcnt lgkmcnt(8)" ::: "memory");
            } else {
                asm volatile("s_waitcnt lgkmcnt(0)" ::: "memory");
            }
            __builtin_amdgcn_sched_barrier(0);

            __builtin_amdgcn_s_setprio(1);
            #pragma unroll
            for (int m = 0; m < 8; ++m)
                #pragma unroll
                for (int n = 0; n < 4; ++n)
                    acc[m][n] = __builtin_amdgcn_mfma_f32_16x16x32_bf16(
                        afN[m], bf[n], acc[m][n], 0, 0, 0);
            __builtin_amdgcn_s_setprio(0);
        }
    }
#undef STAGE

    int row_base = bm * BM2 + wr * 128;
    int col_base = bn * BN2 + wc * 64;
    #pragma unroll
    for (int n = 0; n < 4; ++n) {
        int col = col_base + n * 16 + fr;
        float sc = scales[col], bi = bias[col];
        #pragma unroll
        for (int m = 0; m < 8; ++m) {
            int m0 = row_base + m * 16 + fq * 4;
            #pragma unroll
            for (int r2 = 0; r2 < 4; ++r2)
                Y[(size_t)(m0 + r2) * N + col] = acc[m][n][r2] * sc + bi;
        }
    }
}

// ---------- fallback (if ws too small / odd dims): tiled fp32, inline dequant --

__global__ __launch_bounds__(256) void qlin_fallback(
    const float* __restrict__ x, const int* __restrict__ pw,
    const float* __restrict__ scales, const float* __restrict__ bias,
    float* __restrict__ Y, int M, int N, int K)
{
    __shared__ float Xs[64][32];
    __shared__ float Ws[64][33];
    int bn = blockIdx.x, bm = blockIdx.y;
    int tid = threadIdx.x;
    int tr = tid >> 4, tc = tid & 15;
    float acc[4][4] = {};
    int K2 = K >> 1;
    for (int kt = 0; kt < K; kt += 32) {
        #pragma unroll
        for (int u = 0; u < 8; ++u) {
            int idx = u * 256 + tid;
            int rr = idx >> 5, cc = idx & 31;
            Xs[rr][cc] = x[(size_t)(bm * 64 + rr) * K + kt + cc];
        }
        #pragma unroll
        for (int u = 0; u < 4; ++u) {
            int idx = u * 256 + tid;
            int rr = idx >> 4, cc = idx & 15;
            int v = pw[(size_t)(bn * 64 + rr) * K2 + (kt >> 1) + cc];
            Ws[rr][cc * 2]     = (float)((v & 15) - 8);
            Ws[rr][cc * 2 + 1] = (float)(((v >> 4) & 15) - 8);
        }
        __syncthreads();
        #pragma unroll 8
        for (int kk = 0; kk < 32; ++kk) {
            float xv[4], wv[4];
            #pragma unroll
            for (int i = 0; i < 4; ++i) xv[i] = Xs[tr * 4 + i][kk];
            #pragma unroll
            for (int j = 0; j < 4; ++j) wv[j] = Ws[tc * 4 + j][kk];
            #pragma unroll
            for (int i = 0; i < 4; ++i)
                #pragma unroll
                for (int j = 0; j < 4; ++j)
                    acc[i][j] += xv[i] * wv[j];
        }
        __syncthreads();
    }
    #pragma unroll
    for (int j = 0; j < 4; ++j) {
        int n = bn * 64 + tc * 4 + j;
        float sc = scales[n], bi = bias[n];
        #pragma unroll
        for (int i = 0; i < 4; ++i) {
            int m = bm * 64 + tr * 4 + i;
            Y[(size_t)m * N + n] = acc[i][j] * sc + bi;
        }
    }
}

// ---------- host ----------

extern "C" void kernel_launch(void* const* d_in, const int* in_sizes, int n_in,
                              void* d_out, int out_size, void* d_ws, size_t ws_size,
                              hipStream_t stream) {
    const float* x      = (const float*)d_in[0];
    const int*   pw     = (const int*)d_in[1];
    const float* scales = (const float*)d_in[2];
    const float* bias   = (const float*)d_in[3];
    float*       y      = (float*)d_out;

    int N = in_sizes[2];                         // 11008
    long long pwe = in_sizes[1];                 // N*K/2
    int K = (int)((2 * pwe) / N);                // 4096
    int M = in_sizes[0] / K;                     // 4096

    size_t xb_bytes = (size_t)M * K * 2;
    size_t wb_bytes = (size_t)N * K * 2;

    bool fits = (ws_size >= xb_bytes + wb_bytes);
    bool dims_ok = (M % 256 == 0) && (N % 256 == 0) && (K % 64 == 0) && (K >= 128);

    if (fits && dims_ok) {
        short* xb = (short*)d_ws;
        short* wb = (short*)((char*)d_ws + xb_bytes);
        int cpr = K / 8;                         // 16B chunks per row
        int nkt = K / 64;
        int ncx = (int)((size_t)M * K / 8);
        hipLaunchKernelGGL(cvt_x_kernel, dim3(2048), dim3(256), 0, stream,
                           (const float4*)x, (uint4*)xb, ncx, cpr, nkt);
        int ncw = (int)(pwe / 4);                // = N*K/8
        hipLaunchKernelGGL(dequant_w_kernel, dim3(2048), dim3(256), 0, stream,
                           (const int4*)pw, (uint4*)wb, ncw, cpr, nkt);
        int nwg = (M / 256) * (N / 256);
        hipLaunchKernelGGL(qlin_gemm256, dim3(nwg), dim3(512), 0, stream,
                           xb, wb, scales, bias, y, M, N, K);
    } else {
        hipLaunchKernelGGL(qlin_fallback, dim3(N / 64, M / 64), dim3(256), 0, stream,
                           x, pw, scales, bias, y, M, N, K);
    }
}

// Round 6
// 432.358 us; speedup vs baseline: 1.0785x; 1.0785x over previous
//
#include <hip/hip_runtime.h>
#include <stdint.h>

typedef __attribute__((ext_vector_type(8))) short bf16x8_t;  // 8 bf16 in 4 VGPRs
typedef __attribute__((ext_vector_type(4))) float f32x4_t;   // MFMA accumulator

// ---------- helpers ----------

__device__ __forceinline__ unsigned short f2bf_rn(float f) {
    unsigned int u = __float_as_uint(f);
    u += 0x7fffu + ((u >> 16) & 1u);   // round-to-nearest-even
    return (unsigned short)(u >> 16);
}

// one packed byte (as int32 in [0,256)) -> two bf16 (q-8), low nibble = even k
__device__ __forceinline__ unsigned int dq2(int v) {
    float f0 = (float)((v & 15) - 8);
    float f1 = (float)(((v >> 4) & 15) - 8);
    return (__float_as_uint(f0) >> 16) | (__float_as_uint(f1) & 0xffff0000u);
}

__device__ __forceinline__ void gload_lds16(const void* g, void* l) {
    __builtin_amdgcn_global_load_lds(
        (__attribute__((address_space(1))) void*)g,
        (__attribute__((address_space(3))) void*)l, 16, 0, 0);
}

// ---------- pre-pass kernels: emit TILED kq-major bf16 layout ----------
// Dest layout (16B chunks): [rowblk256][kt(K/64)][kq(4)][slot(512)]
//   slot = (row&255)*2 + chp,  chp = (kc&1) ^ ((row>>2)&1)   (bank swizzle)
// Each kq block (8 KB) is CONTIGUOUS -> GEMM stages it linearly via
// global_load_lds; fragment ds_reads use chp=(fq&1)^((fr>>2)&1) ->
// conflict-free (verified R2/R4: SQ_LDS_BANK_CONFLICT = 0).

__device__ __forceinline__ int tiled_dest(int r, int kc, int nkt) {
    int rb = r & 255;
    int kt = kc >> 3, kcl = kc & 7;
    int kq = kcl >> 1, ch = kcl & 1;
    int chp = ch ^ ((rb >> 2) & 1);
    return ((((r >> 8) * nkt + kt) * 4 + kq) << 9) + rb * 2 + chp;
}

__global__ void cvt_x_kernel(const float4* __restrict__ x4,
                             uint4* __restrict__ o4, int nchunks, int cpr, int nkt) {
    int stride = gridDim.x * blockDim.x;
    for (int i = blockIdx.x * blockDim.x + threadIdx.x; i < nchunks; i += stride) {
        int r = i / cpr, kc = i - r * cpr;
        float4 v0 = x4[2 * i];
        float4 v1 = x4[2 * i + 1];
        uint4 o;
        o.x = (unsigned)f2bf_rn(v0.x) | ((unsigned)f2bf_rn(v0.y) << 16);
        o.y = (unsigned)f2bf_rn(v0.z) | ((unsigned)f2bf_rn(v0.w) << 16);
        o.z = (unsigned)f2bf_rn(v1.x) | ((unsigned)f2bf_rn(v1.y) << 16);
        o.w = (unsigned)f2bf_rn(v1.z) | ((unsigned)f2bf_rn(v1.w) << 16);
        o4[tiled_dest(r, kc, nkt)] = o;
    }
}

__global__ void dequant_w_kernel(const int4* __restrict__ pw4,
                                 uint4* __restrict__ o4, int nchunks, int cpr, int nkt) {
    int stride = gridDim.x * blockDim.x;
    for (int i = blockIdx.x * blockDim.x + threadIdx.x; i < nchunks; i += stride) {
        int r = i / cpr, kc = i - r * cpr;
        int4 v = pw4[i];
        uint4 o;
        o.x = dq2(v.x); o.y = dq2(v.y); o.z = dq2(v.z); o.w = dq2(v.w);
        o4[tiled_dest(r, kc, nkt)] = o;
    }
}

// ---------- main GEMM: 256x256x64, 8 waves, ONE sync/tile, compiler-piped ----
// Per tile t: vmcnt(0) [STAGE(t) issued mid-body t-1, ~2000+cyc in flight ->
// ~free drain; per-wave gate BEFORE barrier = correct cross-wave publish] ->
// s_barrier -> sched_barrier(0) [pin reads below barrier] -> issue ALL 24
// frag ds_reads (before STAGE so the backend can't conservatively order them
// after the aliasing LDS-DMA writes) -> STAGE(t+1) -> 64 MFMA with
// COMPILER-managed counted lgkmcnt (no asm lgkm, no pins: in-order LDS
// retirement lets MFMA m run while a[m+1..7] still stream = intra-wave
// overlap; 1 barrier/tile lets waves skew = inter-wave overlap).
// Race ledger: RAW: own vmcnt(0) then barrier -> all waves' staging of t
// retired before any read. WAR: STAGE(t+1) writes buf[(t+1)&1], last read
// in body t-1; those reads are data-complete before barrier(t), and
// STAGE(t+1) is issued after barrier(t).

__global__ __launch_bounds__(512, 2) void qlin_gemm256(
    const short* __restrict__ Xb, const short* __restrict__ Wb,
    const float* __restrict__ scales, const float* __restrict__ bias,
    float* __restrict__ Y, int M, int N, int K)
{
    __shared__ short As[2][4][4096];   // [buf][kq][512 slots x 8 shorts] = 64 KB
    __shared__ short Bs[2][4][4096];   // 64 KB

    int nbm = M >> 8, nbn = N >> 8, nkt = K >> 6;
    int nwg = nbm * nbn;
    // bijective XCD swizzle (m204 form)
    int bid = blockIdx.x;
    int q8 = nwg >> 3, r8 = nwg & 7;
    int xcd = bid & 7, lid = bid >> 3;
    int wgid = (xcd < r8 ? xcd * (q8 + 1) : r8 * (q8 + 1) + (xcd - r8) * q8) + lid;
    int bm = wgid % nbm, bn = wgid / nbm;

    const short* ga = Xb + (size_t)bm * nkt * 16384;
    const short* gb = Wb + (size_t)bn * nkt * 16384;

    int tid = threadIdx.x, lane = tid & 63, wid = tid >> 6;
    int wr = wid >> 2, wc = wid & 3;          // 2x4 wave grid, per-wave out 128x64
    int fr = lane & 15, fq = lane >> 4;       // frag row / k-subchunk
    int chp = (fq & 1) ^ ((fr >> 2) & 1);     // lane-constant chunk swizzle

    f32x4_t acc[8][4] = {};

    int lsel = (fq >> 1) * 4096 + fr * 16 + chp * 8;
    int arow = wr * 2048;                     // (wr*128 rows)*16 shorts
    int brow = wc * 1024;                     // (wc*64 rows)*16 shorts

#define STAGE(tt)                                                             \
    do {                                                                      \
        int b_ = (tt) & 1;                                                    \
        size_t base_ = (size_t)(tt) * 16384;                                  \
        _Pragma("unroll")                                                     \
        for (int kq_ = 0; kq_ < 4; ++kq_) {                                   \
            gload_lds16(ga + base_ + kq_ * 4096 + tid * 8,                    \
                        &As[b_][kq_][wid * 512]);                             \
            gload_lds16(gb + base_ + kq_ * 4096 + tid * 8,                    \
                        &Bs[b_][kq_][wid * 512]);                             \
        }                                                                     \
    } while (0)

    // prologue: stage tile 0
    STAGE(0);

    int nt = nkt;
    for (int t = 0; t < nt; ++t) {
        asm volatile("s_waitcnt vmcnt(0)" ::: "memory");
        __builtin_amdgcn_s_barrier();
        __builtin_amdgcn_sched_barrier(0);

        const short* Ab = &As[t & 1][0][0];
        const short* Bb = &Bs[t & 1][0][0];

        bf16x8_t b[4][2], a[8][2];
        #pragma unroll
        for (int n = 0; n < 4; ++n)
            #pragma unroll
            for (int h = 0; h < 2; ++h)
                b[n][h] = *(const bf16x8_t*)&Bb[h * 8192 + lsel + brow + n * 256];
        #pragma unroll
        for (int m = 0; m < 8; ++m)
            #pragma unroll
            for (int h = 0; h < 2; ++h)
                a[m][h] = *(const bf16x8_t*)&Ab[h * 8192 + lsel + arow + m * 256];

        if (t + 1 < nt) STAGE(t + 1);

        __builtin_amdgcn_s_setprio(1);
        #pragma unroll
        for (int m = 0; m < 8; ++m)
            #pragma unroll
            for (int h = 0; h < 2; ++h)
                #pragma unroll
                for (int n = 0; n < 4; ++n)
                    acc[m][n] = __builtin_amdgcn_mfma_f32_16x16x32_bf16(
                        a[m][h], b[n][h], acc[m][n], 0, 0, 0);
        __builtin_amdgcn_s_setprio(0);
    }
#undef STAGE

    int row_base = bm * 256 + wr * 128;
    int col_base = bn * 256 + wc * 64;
    #pragma unroll
    for (int n = 0; n < 4; ++n) {
        int col = col_base + n * 16 + fr;
        float sc = scales[col], bi = bias[col];
        #pragma unroll
        for (int m = 0; m < 8; ++m) {
            int m0 = row_base + m * 16 + fq * 4;
            #pragma unroll
            for (int r2 = 0; r2 < 4; ++r2)
                Y[(size_t)(m0 + r2) * N + col] = acc[m][n][r2] * sc + bi;
        }
    }
}

// ---------- fallback (if ws too small / odd dims): tiled fp32, inline dequant --

__global__ __launch_bounds__(256) void qlin_fallback(
    const float* __restrict__ x, const int* __restrict__ pw,
    const float* __restrict__ scales, const float* __restrict__ bias,
    float* __restrict__ Y, int M, int N, int K)
{
    __shared__ float Xs[64][32];
    __shared__ float Ws[64][33];
    int bn = blockIdx.x, bm = blockIdx.y;
    int tid = threadIdx.x;
    int tr = tid >> 4, tc = tid & 15;
    float acc[4][4] = {};
    int K2 = K >> 1;
    for (int kt = 0; kt < K; kt += 32) {
        #pragma unroll
        for (int u = 0; u < 8; ++u) {
            int idx = u * 256 + tid;
            int rr = idx >> 5, cc = idx & 31;
            Xs[rr][cc] = x[(size_t)(bm * 64 + rr) * K + kt + cc];
        }
        #pragma unroll
        for (int u = 0; u < 4; ++u) {
            int idx = u * 256 + tid;
            int rr = idx >> 4, cc = idx & 15;
            int v = pw[(size_t)(bn * 64 + rr) * K2 + (kt >> 1) + cc];
            Ws[rr][cc * 2]     = (float)((v & 15) - 8);
            Ws[rr][cc * 2 + 1] = (float)(((v >> 4) & 15) - 8);
        }
        __syncthreads();
        #pragma unroll 8
        for (int kk = 0; kk < 32; ++kk) {
            float xv[4], wv[4];
            #pragma unroll
            for (int i = 0; i < 4; ++i) xv[i] = Xs[tr * 4 + i][kk];
            #pragma unroll
            for (int j = 0; j < 4; ++j) wv[j] = Ws[tc * 4 + j][kk];
            #pragma unroll
            for (int i = 0; i < 4; ++i)
                #pragma unroll
                for (int j = 0; j < 4; ++j)
                    acc[i][j] += xv[i] * wv[j];
        }
        __syncthreads();
    }
    #pragma unroll
    for (int j = 0; j < 4; ++j) {
        int n = bn * 64 + tc * 4 + j;
        float sc = scales[n], bi = bias[n];
        #pragma unroll
        for (int i = 0; i < 4; ++i) {
            int m = bm * 64 + tr * 4 + i;
            Y[(size_t)m * N + n] = acc[i][j] * sc + bi;
        }
    }
}

// ---------- host ----------

extern "C" void kernel_launch(void* const* d_in, const int* in_sizes, int n_in,
                              void* d_out, int out_size, void* d_ws, size_t ws_size,
                              hipStream_t stream) {
    const float* x      = (const float*)d_in[0];
    const int*   pw     = (const int*)d_in[1];
    const float* scales = (const float*)d_in[2];
    const float* bias   = (const float*)d_in[3];
    float*       y      = (float*)d_out;

    int N = in_sizes[2];                         // 11008
    long long pwe = in_sizes[1];                 // N*K/2
    int K = (int)((2 * pwe) / N);                // 4096
    int M = in_sizes[0] / K;                     // 4096

    size_t xb_bytes = (size_t)M * K * 2;
    size_t wb_bytes = (size_t)N * K * 2;

    bool fits = (ws_size >= xb_bytes + wb_bytes);
    bool dims_ok = (M % 256 == 0) && (N % 256 == 0) && (K % 64 == 0) && (K >= 128);

    if (fits && dims_ok) {
        short* xb = (short*)d_ws;
        short* wb = (short*)((char*)d_ws + xb_bytes);
        int cpr = K / 8;                         // 16B chunks per row
        int nkt = K / 64;
        int ncx = (int)((size_t)M * K / 8);
        hipLaunchKernelGGL(cvt_x_kernel, dim3(2048), dim3(256), 0, stream,
                           (const float4*)x, (uint4*)xb, ncx, cpr, nkt);
        int ncw = (int)(pwe / 4);                // = N*K/8
        hipLaunchKernelGGL(dequant_w_kernel, dim3(2048), dim3(256), 0, stream,
                           (const int4*)pw, (uint4*)wb, ncw, cpr, nkt);
        int nwg = (M / 256) * (N / 256);
        hipLaunchKernelGGL(qlin_gemm256, dim3(nwg), dim3(512), 0, stream,
                           xb, wb, scales, bias, y, M, N, K);
    } else {
        hipLaunchKernelGGL(qlin_fallback, dim3(N / 64, M / 64), dim3(256), 0, stream,
                           x, pw, scales, bias, y, M, N, K);
    }
}